// Round 1
// baseline (214.258 us; speedup 1.0000x reference)
//
#include <hip/hip_runtime.h>
#include <hip/hip_bf16.h>

#define NHEADS 12
#define NFRAMES 8
#define NTOK 1568
#define CDIM 768
#define DHEAD 64
#define BATCH 2
#define MROWS (BATCH * NTOK) /* 3136 */
#define MPAD 3200
#define K3 (3 * CDIM)        /* 2304 */
#define AREA1 197
#define TPF 196

typedef __bf16 bf16x8 __attribute__((ext_vector_type(8)));
typedef float f32x4 __attribute__((ext_vector_type(4)));
typedef unsigned short u16x8 __attribute__((ext_vector_type(8)));

__device__ __forceinline__ unsigned short f2bf(float f) {
  return __builtin_bit_cast(unsigned short, (__bf16)f);
}
__device__ __forceinline__ bf16x8 ld8(const unsigned short* p) {
  return __builtin_bit_cast(bf16x8, *(const u16x8*)p);
}
__device__ __forceinline__ f32x4 mfma16(bf16x8 a, bf16x8 b, f32x4 c) {
  return __builtin_amdgcn_mfma_f32_16x16x32_bf16(a, b, c, 0, 0, 0);
}

// ---------------- conversion / packing ----------------
__global__ void conv_kernel(const float* __restrict__ x,
                            const float* __restrict__ qkv_w,
                            const float* __restrict__ proj_w,
                            unsigned short* __restrict__ xb,
                            unsigned short* __restrict__ qkvwb,
                            unsigned short* __restrict__ projwb,
                            unsigned short* __restrict__ aout) {
  const int XCH = MPAD * CDIM / 4;
  const int WCH = K3 * CDIM / 4;
  const int PCH = CDIM * CDIM / 4;
  const int ACH = (MPAD - MROWS) * CDIM / 4;
  const int total = XCH + WCH + PCH + ACH;
  for (int c = blockIdx.x * blockDim.x + threadIdx.x; c < total;
       c += gridDim.x * blockDim.x) {
    if (c < XCH) {
      int m = (c * 4) / CDIM;
      float4 v = make_float4(0.f, 0.f, 0.f, 0.f);
      if (m < MROWS) v = ((const float4*)x)[c];
      ushort4 o;
      o.x = f2bf(v.x); o.y = f2bf(v.y); o.z = f2bf(v.z); o.w = f2bf(v.w);
      ((ushort4*)xb)[c] = o;
    } else if (c < XCH + WCH) {
      int c2 = c - XCH;
      float4 v = ((const float4*)qkv_w)[c2];
      ushort4 o;
      o.x = f2bf(v.x); o.y = f2bf(v.y); o.z = f2bf(v.z); o.w = f2bf(v.w);
      ((ushort4*)qkvwb)[c2] = o;
    } else if (c < XCH + WCH + PCH) {
      int c2 = c - XCH - WCH;
      float4 v = ((const float4*)proj_w)[c2];
      ushort4 o;
      o.x = f2bf(v.x); o.y = f2bf(v.y); o.z = f2bf(v.z); o.w = f2bf(v.w);
      ((ushort4*)projwb)[c2] = o;
    } else {
      int c2 = c - XCH - WCH - PCH;
      ushort4 z; z.x = 0; z.y = 0; z.z = 0; z.w = 0;
      ((ushort4*)(aout + (size_t)MROWS * CDIM))[c2] = z;
    }
  }
}

// ---------------- bias table pre-gather ----------------
__global__ void bias_kernel(const float* __restrict__ rpt,
                            const float* __restrict__ rtt,
                            const int* __restrict__ rpi,
                            const int* __restrict__ rti,
                            float* __restrict__ bias1,
                            float* __restrict__ bias2) {
  int t = blockIdx.x * blockDim.x + threadIdx.x;
  const int n1 = NHEADS * AREA1 * AREA1;
  if (t < n1) {
    int h = t / (AREA1 * AREA1);
    int ij = t - h * (AREA1 * AREA1);
    bias1[t] = rpt[rpi[ij] * NHEADS + h];
  } else if (t < n1 + NHEADS * 64) {
    int t2 = t - n1;
    int h = t2 >> 6, ff = t2 & 63;
    bias2[t2] = rtt[rti[ff] * NHEADS + h];
  }
}

// ---------------- 128x128 MFMA GEMM (NT: both A,B row-major over K) ----------------
// MODE 0: qkv projection epilogue (scatter q/k/v^T, biases, q*0.125)
// MODE 1: output projection epilogue (fp32 + proj_b -> d_out)
template <int MODE>
__global__ __launch_bounds__(256) void gemm_kernel(
    const unsigned short* __restrict__ A,
    const unsigned short* __restrict__ Bw,
    const float* __restrict__ bias0,   // q_bias (MODE0) / proj_b (MODE1)
    const float* __restrict__ biasv,   // v_bias (MODE0)
    unsigned short* __restrict__ qbuf,
    unsigned short* __restrict__ kbuf,
    unsigned short* __restrict__ vtbuf,
    float* __restrict__ Cout) {
  __shared__ unsigned short As[2][128 * 32];
  __shared__ unsigned short Bs[2][128 * 32];
  const int lane = threadIdx.x & 63;
  const int wv = threadIdx.x >> 6;
  const int m0 = blockIdx.y * 128;
  const int n0 = blockIdx.x * 128;

  auto stage = [&](int buf, int kt) {
    const int k0 = kt * 32;
#pragma unroll
    for (int issue = 0; issue < 2; ++issue) {
      const int c = issue * 256 + wv * 64 + lane;
      const int r = c >> 2;
      const int seg = c & 3;
      const unsigned short* ga = A + (size_t)(m0 + r) * CDIM + k0 + seg * 8;
      const unsigned short* gb = Bw + (size_t)(n0 + r) * CDIM + k0 + seg * 8;
      __builtin_amdgcn_global_load_lds(
          (const __attribute__((address_space(1))) void*)ga,
          (__attribute__((address_space(3))) void*)&As[buf][(issue * 256 + wv * 64) * 8],
          16, 0, 0);
      __builtin_amdgcn_global_load_lds(
          (const __attribute__((address_space(1))) void*)gb,
          (__attribute__((address_space(3))) void*)&Bs[buf][(issue * 256 + wv * 64) * 8],
          16, 0, 0);
    }
  };

  f32x4 acc[4][4] = {};
  const int rbase = (wv >> 1) * 64;
  const int cbase = (wv & 1) * 64;

  stage(0, 0);
  __syncthreads();
  int cur = 0;
  for (int kt = 0; kt < CDIM / 32; ++kt) {
    if (kt + 1 < CDIM / 32) stage(cur ^ 1, kt + 1);
    bf16x8 af[4], bg[4];
#pragma unroll
    for (int i = 0; i < 4; ++i) {
      af[i] = ld8(&As[cur][(rbase + i * 16 + (lane & 15)) * 32 + (lane >> 4) * 8]);
      bg[i] = ld8(&Bs[cur][(cbase + i * 16 + (lane & 15)) * 32 + (lane >> 4) * 8]);
    }
#pragma unroll
    for (int i = 0; i < 4; ++i)
#pragma unroll
      for (int j = 0; j < 4; ++j)
        acc[i][j] = mfma16(af[i], bg[j], acc[i][j]);
    __syncthreads();
    cur ^= 1;
  }

#pragma unroll
  for (int i = 0; i < 4; ++i) {
#pragma unroll
    for (int j = 0; j < 4; ++j) {
#pragma unroll
      for (int r = 0; r < 4; ++r) {
        int grow = m0 + rbase + i * 16 + (lane >> 4) * 4 + r;
        int gcol = n0 + cbase + j * 16 + (lane & 15);
        if (grow >= MROWS) continue;
        float v = acc[i][j][r];
        if (MODE == 0) {
          int which = gcol / CDIM;
          int cc = gcol - which * CDIM;
          int hh = cc >> 6, dd = cc & 63;
          int b = grow / NTOK, n = grow - b * NTOK;
          size_t hd = ((size_t)(b * NHEADS + hh) * NTOK + n) * 64 + dd;
          if (which == 0)
            qbuf[hd] = f2bf((v + bias0[cc]) * 0.125f);
          else if (which == 1)
            kbuf[hd] = f2bf(v);
          else
            vtbuf[((size_t)(b * NHEADS + hh) * 64 + dd) * NTOK + n] =
                f2bf(v + biasv[cc]);
        } else {
          Cout[(size_t)grow * CDIM + gcol] = v + bias0[gcol];
        }
      }
    }
  }
}

// ---------------- flash attention ----------------
// grid: (25 q-blocks of 64 rows, 24 b*h). block: 256 thr = 4 waves x 16 q-rows.
__global__ __launch_bounds__(256) void attn_kernel(
    const unsigned short* __restrict__ qbuf,
    const unsigned short* __restrict__ kbuf,
    const unsigned short* __restrict__ vtbuf,
    const float* __restrict__ bias1,
    const float* __restrict__ bias2,
    unsigned short* __restrict__ aout) {
  __shared__ unsigned short plds[4][16 * 56];  // per-wave P tile, stride 56 (112B rows)
  const int lane = threadIdx.x & 63;
  const int wv = threadIdx.x >> 6;
  const int bh = blockIdx.y;   // 0..23
  const int q0 = blockIdx.x * 64 + wv * 16;
  if (q0 >= NTOK) return;
  const int h = bh % NHEADS;
  const int b = bh / NHEADS;
  const float* b1h = bias1 + (size_t)h * AREA1 * AREA1;
  const float* b2h = bias2 + h * 64;
  const unsigned short* qp = qbuf + (size_t)bh * NTOK * DHEAD;
  const unsigned short* kp = kbuf + (size_t)bh * NTOK * DHEAD;
  const unsigned short* vp = vtbuf + (size_t)bh * DHEAD * NTOK;

  const bf16x8 aq0 = ld8(qp + (size_t)(q0 + (lane & 15)) * DHEAD + ((lane >> 4) * 8));
  const bf16x8 aq1 = ld8(qp + (size_t)(q0 + (lane & 15)) * DHEAD + 32 + ((lane >> 4) * 8));

  int qmod[4], qfr[4];
#pragma unroll
  for (int r = 0; r < 4; ++r) {
    int qn = q0 + (lane >> 4) * 4 + r;
    qmod[r] = qn % AREA1;
    qfr[r] = qn / TPF;
  }

  f32x4 accd[4] = {};
  float mrun[4], lrun[4];
#pragma unroll
  for (int r = 0; r < 4; ++r) { mrun[r] = -3.0e38f; lrun[r] = 0.f; }

  unsigned short* pl = plds[wv];

  for (int kt = 0; kt < NTOK / 32; ++kt) {
    const int kv0 = kt * 32;
    bf16x8 bk00 = ld8(kp + (size_t)(kv0 + (lane & 15)) * DHEAD + ((lane >> 4) * 8));
    bf16x8 bk01 = ld8(kp + (size_t)(kv0 + (lane & 15)) * DHEAD + 32 + ((lane >> 4) * 8));
    bf16x8 bk10 = ld8(kp + (size_t)(kv0 + 16 + (lane & 15)) * DHEAD + ((lane >> 4) * 8));
    bf16x8 bk11 = ld8(kp + (size_t)(kv0 + 16 + (lane & 15)) * DHEAD + 32 + ((lane >> 4) * 8));
    f32x4 s0 = {}, s1 = {};
    s0 = mfma16(aq0, bk00, s0);
    s0 = mfma16(aq1, bk01, s0);
    s1 = mfma16(aq0, bk10, s1);
    s1 = mfma16(aq1, bk11, s1);

    const int kn0 = kv0 + (lane & 15);
    const int kn1 = kn0 + 16;
    const int km0 = kn0 % AREA1, km1 = kn1 % AREA1;
    const int kf0 = kn0 / TPF, kf1 = kn1 / TPF;
#pragma unroll
    for (int r = 0; r < 4; ++r) {
      s0[r] += b1h[qmod[r] * AREA1 + km0] + b2h[qfr[r] * 8 + kf0];
      s1[r] += b1h[qmod[r] * AREA1 + km1] + b2h[qfr[r] * 8 + kf1];
    }

    float fac[4], p0[4], p1[4];
#pragma unroll
    for (int r = 0; r < 4; ++r) {
      float tm = fmaxf(s0[r], s1[r]);
      tm = fmaxf(tm, __shfl_xor(tm, 1));
      tm = fmaxf(tm, __shfl_xor(tm, 2));
      tm = fmaxf(tm, __shfl_xor(tm, 4));
      tm = fmaxf(tm, __shfl_xor(tm, 8));
      float mnew = fmaxf(mrun[r], tm);
      fac[r] = __expf(mrun[r] - mnew);
      mrun[r] = mnew;
      p0[r] = __expf(s0[r] - mnew);
      p1[r] = __expf(s1[r] - mnew);
      float ts = p0[r] + p1[r];
      ts += __shfl_xor(ts, 1);
      ts += __shfl_xor(ts, 2);
      ts += __shfl_xor(ts, 4);
      ts += __shfl_xor(ts, 8);
      lrun[r] = lrun[r] * fac[r] + ts;
    }
#pragma unroll
    for (int dt = 0; dt < 4; ++dt)
#pragma unroll
      for (int r = 0; r < 4; ++r) accd[dt][r] *= fac[r];

#pragma unroll
    for (int r = 0; r < 4; ++r) {
      int row = (lane >> 4) * 4 + r;
      pl[row * 56 + (lane & 15)] = f2bf(p0[r]);
      pl[row * 56 + 16 + (lane & 15)] = f2bf(p1[r]);
    }
    __asm__ volatile("s_waitcnt lgkmcnt(0)" ::: "memory");
    bf16x8 pa = ld8(&pl[(lane & 15) * 56 + (lane >> 4) * 8]);
#pragma unroll
    for (int dt = 0; dt < 4; ++dt) {
      bf16x8 bv = ld8(vp + (size_t)(dt * 16 + (lane & 15)) * NTOK + kv0 + (lane >> 4) * 8);
      accd[dt] = mfma16(pa, bv, accd[dt]);
    }
  }

  float rinv[4];
#pragma unroll
  for (int r = 0; r < 4; ++r) rinv[r] = 1.0f / lrun[r];
#pragma unroll
  for (int dt = 0; dt < 4; ++dt) {
#pragma unroll
    for (int r = 0; r < 4; ++r) {
      int row = q0 + (lane >> 4) * 4 + r;
      int col = h * 64 + dt * 16 + (lane & 15);
      aout[(size_t)(b * NTOK + row) * CDIM + col] = f2bf(accd[dt][r] * rinv[r]);
    }
  }
}

extern "C" void kernel_launch(void* const* d_in, const int* in_sizes, int n_in,
                              void* d_out, int out_size, void* d_ws, size_t ws_size,
                              hipStream_t stream) {
  (void)in_sizes; (void)n_in; (void)out_size; (void)ws_size;
  const float* x        = (const float*)d_in[0];
  const float* qkv_w    = (const float*)d_in[1];
  const float* q_bias   = (const float*)d_in[2];
  const float* v_bias   = (const float*)d_in[3];
  const float* rp_table = (const float*)d_in[4];
  const float* rt_table = (const float*)d_in[5];
  const float* proj_w   = (const float*)d_in[6];
  const float* proj_b   = (const float*)d_in[7];
  const int* rp_index   = (const int*)d_in[8];
  const int* rt_index   = (const int*)d_in[9];

  char* ws = (char*)d_ws;
  unsigned short* xb     = (unsigned short*)(ws);
  unsigned short* qkvwb  = (unsigned short*)(ws + 4915200);
  unsigned short* projwb = (unsigned short*)(ws + 8454144);
  unsigned short* qbuf   = (unsigned short*)(ws + 9633792);
  unsigned short* kbuf   = (unsigned short*)(ws + 14450688);
  unsigned short* vtbuf  = (unsigned short*)(ws + 19267584);
  unsigned short* aout   = (unsigned short*)(ws + 24084480);
  float* bias1           = (float*)(ws + 28999680);
  float* bias2           = (float*)(ws + 30862512);

  conv_kernel<<<2048, 256, 0, stream>>>(x, qkv_w, proj_w, xb, qkvwb, projwb, aout);
  bias_kernel<<<(NHEADS * AREA1 * AREA1 + NHEADS * 64 + 255) / 256, 256, 0, stream>>>(
      rp_table, rt_table, rp_index, rt_index, bias1, bias2);
  gemm_kernel<0><<<dim3(K3 / 128, MPAD / 128), 256, 0, stream>>>(
      xb, qkvwb, q_bias, v_bias, qbuf, kbuf, vtbuf, nullptr);
  attn_kernel<<<dim3(25, BATCH * NHEADS), 256, 0, stream>>>(
      qbuf, kbuf, vtbuf, bias1, bias2, aout);
  gemm_kernel<1><<<dim3(CDIM / 128, MPAD / 128), 256, 0, stream>>>(
      aout, projwb, proj_b, nullptr, nullptr, nullptr, nullptr, (float*)d_out);
}

// Round 2
// 178.863 us; speedup vs baseline: 1.1979x; 1.1979x over previous
//
#include <hip/hip_runtime.h>
#include <hip/hip_bf16.h>

#define NHEADS 12
#define NFRAMES 8
#define NTOK 1568
#define CDIM 768
#define DHEAD 64
#define BATCH 2
#define MROWS (BATCH * NTOK) /* 3136 */
#define MPAD 3200
#define K3 (3 * CDIM)        /* 2304 */
#define AREA1 197
#define EXT1 228
#define TPF 196

typedef __bf16 bf16x8 __attribute__((ext_vector_type(8)));
typedef float f32x4 __attribute__((ext_vector_type(4)));
typedef float f32x16 __attribute__((ext_vector_type(16)));
typedef unsigned short u16x8 __attribute__((ext_vector_type(8)));

__device__ __forceinline__ unsigned short f2bf(float f) {
  return __builtin_bit_cast(unsigned short, (__bf16)f);
}
__device__ __forceinline__ float bf2f(unsigned short u) {
  unsigned int x = ((unsigned int)u) << 16;
  return __builtin_bit_cast(float, x);
}
__device__ __forceinline__ bf16x8 ld8(const unsigned short* p) {
  return __builtin_bit_cast(bf16x8, *(const u16x8*)p);
}
__device__ __forceinline__ f32x4 mfma16(bf16x8 a, bf16x8 b, f32x4 c) {
  return __builtin_amdgcn_mfma_f32_16x16x32_bf16(a, b, c, 0, 0, 0);
}
__device__ __forceinline__ f32x16 mfma32(bf16x8 a, bf16x8 b, f32x16 c) {
  return __builtin_amdgcn_mfma_f32_32x32x16_bf16(a, b, c, 0, 0, 0);
}
__device__ __forceinline__ unsigned int pack2(float lo, float hi) {
  return ((unsigned int)f2bf(hi) << 16) | (unsigned int)f2bf(lo);
}

// ---------------- conversion / packing ----------------
__global__ void conv_kernel(const float* __restrict__ x,
                            const float* __restrict__ qkv_w,
                            const float* __restrict__ proj_w,
                            unsigned short* __restrict__ xb,
                            unsigned short* __restrict__ qkvwb,
                            unsigned short* __restrict__ projwb,
                            unsigned short* __restrict__ aout) {
  const int XCH = MPAD * CDIM / 4;
  const int WCH = K3 * CDIM / 4;
  const int PCH = CDIM * CDIM / 4;
  const int ACH = (MPAD - MROWS) * CDIM / 4;
  const int total = XCH + WCH + PCH + ACH;
  for (int c = blockIdx.x * blockDim.x + threadIdx.x; c < total;
       c += gridDim.x * blockDim.x) {
    if (c < XCH) {
      int m = (c * 4) / CDIM;
      float4 v = make_float4(0.f, 0.f, 0.f, 0.f);
      if (m < MROWS) v = ((const float4*)x)[c];
      ushort4 o;
      o.x = f2bf(v.x); o.y = f2bf(v.y); o.z = f2bf(v.z); o.w = f2bf(v.w);
      ((ushort4*)xb)[c] = o;
    } else if (c < XCH + WCH) {
      int c2 = c - XCH;
      float4 v = ((const float4*)qkv_w)[c2];
      ushort4 o;
      o.x = f2bf(v.x); o.y = f2bf(v.y); o.z = f2bf(v.z); o.w = f2bf(v.w);
      ((ushort4*)qkvwb)[c2] = o;
    } else if (c < XCH + WCH + PCH) {
      int c2 = c - XCH - WCH;
      float4 v = ((const float4*)proj_w)[c2];
      ushort4 o;
      o.x = f2bf(v.x); o.y = f2bf(v.y); o.z = f2bf(v.z); o.w = f2bf(v.w);
      ((ushort4*)projwb)[c2] = o;
    } else {
      int c2 = c - XCH - WCH - PCH;
      ushort4 z; z.x = 0; z.y = 0; z.z = 0; z.w = 0;
      ((ushort4*)(aout + (size_t)MROWS * CDIM))[c2] = z;
    }
  }
}

// ---------------- bias table pre-gather ----------------
// bias1T[h][j=km_ext<228][i=qmod_ext<228] (bf16), periodic extension of the
// transposed gathered 2D table; bias2[h][qframe][kframe] (fp32).
__global__ void bias_kernel(const float* __restrict__ rpt,
                            const float* __restrict__ rtt,
                            const int* __restrict__ rpi,
                            const int* __restrict__ rti,
                            unsigned short* __restrict__ bias1T,
                            float* __restrict__ bias2) {
  int t = blockIdx.x * blockDim.x + threadIdx.x;
  const int n1 = NHEADS * EXT1 * EXT1;
  if (t < n1) {
    int h = t / (EXT1 * EXT1);
    int rem = t - h * (EXT1 * EXT1);
    int j = rem / EXT1;
    int i = rem - j * EXT1;
    int jm = (j >= AREA1) ? j - AREA1 : j;
    int im = (i >= AREA1) ? i - AREA1 : i;
    bias1T[t] = f2bf(rpt[rpi[im * AREA1 + jm] * NHEADS + h]);
  } else if (t < n1 + NHEADS * 64) {
    int t2 = t - n1;
    int h = t2 >> 6, ff = t2 & 63;
    bias2[t2] = rtt[rti[ff] * NHEADS + h];
  }
}

// ---------------- 128x128 MFMA GEMM (NT: both A,B row-major over K) ----------------
template <int MODE>
__global__ __launch_bounds__(256) void gemm_kernel(
    const unsigned short* __restrict__ A,
    const unsigned short* __restrict__ Bw,
    const float* __restrict__ bias0,   // q_bias (MODE0) / proj_b (MODE1)
    const float* __restrict__ biasv,   // v_bias (MODE0)
    unsigned short* __restrict__ qbuf,
    unsigned short* __restrict__ kbuf,
    unsigned short* __restrict__ vtbuf,
    float* __restrict__ Cout) {
  __shared__ unsigned short As[2][128 * 32];
  __shared__ unsigned short Bs[2][128 * 32];
  const int lane = threadIdx.x & 63;
  const int wv = threadIdx.x >> 6;
  const int m0 = blockIdx.y * 128;
  const int n0 = blockIdx.x * 128;

  auto stage = [&](int buf, int kt) {
    const int k0 = kt * 32;
#pragma unroll
    for (int issue = 0; issue < 2; ++issue) {
      const int c = issue * 256 + wv * 64 + lane;
      const int r = c >> 2;
      const int seg = c & 3;
      const unsigned short* ga = A + (size_t)(m0 + r) * CDIM + k0 + seg * 8;
      const unsigned short* gb = Bw + (size_t)(n0 + r) * CDIM + k0 + seg * 8;
      __builtin_amdgcn_global_load_lds(
          (const __attribute__((address_space(1))) void*)ga,
          (__attribute__((address_space(3))) void*)&As[buf][(issue * 256 + wv * 64) * 8],
          16, 0, 0);
      __builtin_amdgcn_global_load_lds(
          (const __attribute__((address_space(1))) void*)gb,
          (__attribute__((address_space(3))) void*)&Bs[buf][(issue * 256 + wv * 64) * 8],
          16, 0, 0);
    }
  };

  f32x4 acc[4][4] = {};
  const int rbase = (wv >> 1) * 64;
  const int cbase = (wv & 1) * 64;

  stage(0, 0);
  __syncthreads();
  int cur = 0;
  for (int kt = 0; kt < CDIM / 32; ++kt) {
    if (kt + 1 < CDIM / 32) stage(cur ^ 1, kt + 1);
    bf16x8 af[4], bg[4];
#pragma unroll
    for (int i = 0; i < 4; ++i) {
      af[i] = ld8(&As[cur][(rbase + i * 16 + (lane & 15)) * 32 + (lane >> 4) * 8]);
      bg[i] = ld8(&Bs[cur][(cbase + i * 16 + (lane & 15)) * 32 + (lane >> 4) * 8]);
    }
#pragma unroll
    for (int i = 0; i < 4; ++i)
#pragma unroll
      for (int j = 0; j < 4; ++j)
        acc[i][j] = mfma16(af[i], bg[j], acc[i][j]);
    __syncthreads();
    cur ^= 1;
  }

#pragma unroll
  for (int i = 0; i < 4; ++i) {
#pragma unroll
    for (int j = 0; j < 4; ++j) {
#pragma unroll
      for (int r = 0; r < 4; ++r) {
        int grow = m0 + rbase + i * 16 + (lane >> 4) * 4 + r;
        int gcol = n0 + cbase + j * 16 + (lane & 15);
        if (grow >= MROWS) continue;
        float v = acc[i][j][r];
        if (MODE == 0) {
          int which = gcol / CDIM;
          int cc = gcol - which * CDIM;
          int hh = cc >> 6, dd = cc & 63;
          int b = grow / NTOK, n = grow - b * NTOK;
          size_t hd = ((size_t)(b * NHEADS + hh) * NTOK + n) * 64 + dd;
          if (which == 0)
            qbuf[hd] = f2bf((v + bias0[cc]) * 0.125f);
          else if (which == 1)
            kbuf[hd] = f2bf(v);
          else
            vtbuf[((size_t)(b * NHEADS + hh) * 64 + dd) * NTOK + n] =
                f2bf(v + biasv[cc]);
        } else {
          Cout[(size_t)grow * CDIM + gcol] = v + bias0[gcol];
        }
      }
    }
  }
}

// ---------------- flash attention v2: swapped QK^T, 32x32 MFMA, no LDS ----------------
// 1176 one-wave units = 24 bh * 49 q-tiles of 32. grid 294 blocks x 4 waves.
__global__ __launch_bounds__(256) void attn_kernel(
    const unsigned short* __restrict__ qbuf,
    const unsigned short* __restrict__ kbuf,
    const unsigned short* __restrict__ vtbuf,
    const unsigned short* __restrict__ bias1T,
    const float* __restrict__ bias2,
    unsigned short* __restrict__ aout) {
  const int lane = threadIdx.x & 63;
  const int wv = threadIdx.x >> 6;
  const int wu = blockIdx.x * 4 + wv;          // 0..1175
  const int bh = wu / 49;
  const int qt = wu - bh * 49;
  const int q0 = qt * 32;
  const int h = bh % NHEADS;
  const int b = bh / NHEADS;
  const int qlane = lane & 31;
  const int hi = lane >> 5;
  const int qn = q0 + qlane;
  const int qfr = qn / TPF;

  const unsigned short* qp = qbuf + (size_t)bh * NTOK * DHEAD;
  const unsigned short* kp = kbuf + (size_t)bh * NTOK * DHEAD;
  const unsigned short* vp = vtbuf + (size_t)bh * DHEAD * NTOK;
  const unsigned short* b1 = bias1T + (size_t)h * EXT1 * EXT1 + (q0 % AREA1) + qlane;
  const float* b2p = bias2 + h * 64 + qfr * 8;

  bf16x8 aq[4];
#pragma unroll
  for (int c = 0; c < 4; ++c)
    aq[c] = ld8(qp + (size_t)qn * DHEAD + c * 16 + hi * 8);

  f32x16 o0 = {}, o1 = {};
  float mrun = -1.0e30f, lrun = 0.f;

  bf16x8 kf[4];
#pragma unroll
  for (int c = 0; c < 4; ++c)
    kf[c] = ld8(kp + (size_t)qlane * DHEAD + c * 16 + hi * 8);

  int base = 0;  // kv0 % 197
  for (int kt = 0; kt < NTOK / 32; ++kt) {
    const int kv0 = kt * 32;
    // S^T = K * Q^T  (32k x 32q), accumulate over 4 D-chunks of 16
    f32x16 s = {};
#pragma unroll
    for (int c = 0; c < 4; ++c) s = mfma32(kf[c], aq[c], s);
    // prefetch next K tile
    if (kt < NTOK / 32 - 1) {
#pragma unroll
      for (int c = 0; c < 4; ++c)
        kf[c] = ld8(kp + (size_t)(kv0 + 32 + qlane) * DHEAD + c * 16 + hi * 8);
    }
    // V fragments for this tile (A-operand of O^T = V^T P^T)
    bf16x8 vf0 = ld8(vp + (size_t)qlane * NTOK + kv0 + hi * 8);
    bf16x8 vf1 = ld8(vp + (size_t)qlane * NTOK + kv0 + 16 + hi * 8);
    bf16x8 vf2 = ld8(vp + (size_t)(32 + qlane) * NTOK + kv0 + hi * 8);
    bf16x8 vf3 = ld8(vp + (size_t)(32 + qlane) * NTOK + kv0 + 16 + hi * 8);

    // bias1: coalesced row loads (lane's qmod is the fast axis)
    float bl[16];
#pragma unroll
    for (int r = 0; r < 16; ++r) {
      const int kit = (r & 3) + 8 * (r >> 2) + 4 * hi;
      bl[r] = bf2f(b1[(size_t)(base + kit) * EXT1]);
    }
    // bias2: at most 2 distinct kframe values per 32-tile
    const int kfl = kv0 / TPF;
    const int bnd = (kfl + 1) * TPF;
    const float b2lo = b2p[kfl];
    const float b2hi = b2p[kfl < 7 ? kfl + 1 : 7];
#pragma unroll
    for (int r = 0; r < 16; ++r) {
      const int kn = kv0 + (r & 3) + 8 * (r >> 2) + 4 * hi;
      s[r] += bl[r] + (kn >= bnd ? b2hi : b2lo);
    }

    // in-register softmax over k (16 regs + one cross-half exchange)
    float tmax = s[0];
#pragma unroll
    for (int r = 1; r < 16; ++r) tmax = fmaxf(tmax, s[r]);
    tmax = fmaxf(tmax, __shfl_xor(tmax, 32));
    if (!__all(tmax - mrun <= 8.0f)) {           // T13 defer-max
      const float mnew = fmaxf(mrun, tmax);
      const float fac = __expf(mrun - mnew);
      lrun *= fac;
#pragma unroll
      for (int r = 0; r < 16; ++r) { o0[r] *= fac; o1[r] *= fac; }
      mrun = mnew;
    }
    float p[16];
#pragma unroll
    for (int r = 0; r < 16; ++r) p[r] = __expf(s[r] - mrun);
    float ps = 0.f;
#pragma unroll
    for (int r = 0; r < 16; ++r) ps += p[r];
    ps += __shfl_xor(ps, 32);
    lrun += ps;

    // pack P -> bf16 pairs; k of reg r is (r&3)+8*(r>>2)+4*hi
    unsigned int dw[8], e[8];
#pragma unroll
    for (int c = 0; c < 8; ++c) dw[c] = pack2(p[2 * c], p[2 * c + 1]);
#pragma unroll
    for (int c = 0; c < 8; ++c) e[c] = __shfl_xor(dw[c], 32);
    // build B-fragments (P^T, k contiguous per half): chunk0 = k0..15, chunk1 = k16..31
    unsigned int f0[4], f1[4];
    f0[0] = hi ? e[2] : dw[0];  f0[1] = hi ? e[3] : dw[1];
    f0[2] = hi ? dw[2] : e[0];  f0[3] = hi ? dw[3] : e[1];
    f1[0] = hi ? e[6] : dw[4];  f1[1] = hi ? e[7] : dw[5];
    f1[2] = hi ? dw[6] : e[4];  f1[3] = hi ? dw[7] : e[5];
    const bf16x8 F0 = __builtin_bit_cast(bf16x8, *(ulonglong2*)f0);
    const bf16x8 F1 = __builtin_bit_cast(bf16x8, *(ulonglong2*)f1);

    o0 = mfma32(vf0, F0, o0);
    o0 = mfma32(vf1, F1, o0);
    o1 = mfma32(vf2, F0, o1);
    o1 = mfma32(vf3, F1, o1);

    base += 32;
    if (base >= AREA1) base -= AREA1;
  }

  const float rinv = 1.0f / lrun;
  unsigned short* op = aout + (size_t)(b * NTOK + qn) * CDIM + h * 64;
#pragma unroll
  for (int c = 0; c < 8; ++c) {
    const int d0 = 8 * (c >> 1) + 4 * hi + 2 * (c & 1);
    *(unsigned int*)(op + d0) = pack2(o0[2 * c] * rinv, o0[2 * c + 1] * rinv);
    *(unsigned int*)(op + 32 + d0) = pack2(o1[2 * c] * rinv, o1[2 * c + 1] * rinv);
  }
}

extern "C" void kernel_launch(void* const* d_in, const int* in_sizes, int n_in,
                              void* d_out, int out_size, void* d_ws, size_t ws_size,
                              hipStream_t stream) {
  (void)in_sizes; (void)n_in; (void)out_size; (void)ws_size;
  const float* x        = (const float*)d_in[0];
  const float* qkv_w    = (const float*)d_in[1];
  const float* q_bias   = (const float*)d_in[2];
  const float* v_bias   = (const float*)d_in[3];
  const float* rp_table = (const float*)d_in[4];
  const float* rt_table = (const float*)d_in[5];
  const float* proj_w   = (const float*)d_in[6];
  const float* proj_b   = (const float*)d_in[7];
  const int* rp_index   = (const int*)d_in[8];
  const int* rt_index   = (const int*)d_in[9];

  char* ws = (char*)d_ws;
  unsigned short* xb     = (unsigned short*)(ws);
  unsigned short* qkvwb  = (unsigned short*)(ws + 4915200);
  unsigned short* projwb = (unsigned short*)(ws + 8454144);
  unsigned short* qbuf   = (unsigned short*)(ws + 9633792);
  unsigned short* kbuf   = (unsigned short*)(ws + 14450688);
  unsigned short* vtbuf  = (unsigned short*)(ws + 19267584);
  unsigned short* aout   = (unsigned short*)(ws + 24084480);
  unsigned short* bias1T = (unsigned short*)(ws + 28999680);
  float* bias2           = (float*)(ws + 30246816);

  conv_kernel<<<2048, 256, 0, stream>>>(x, qkv_w, proj_w, xb, qkvwb, projwb, aout);
  bias_kernel<<<(NHEADS * EXT1 * EXT1 + NHEADS * 64 + 255) / 256, 256, 0, stream>>>(
      rp_table, rt_table, rp_index, rt_index, bias1T, bias2);
  gemm_kernel<0><<<dim3(K3 / 128, MPAD / 128), 256, 0, stream>>>(
      xb, qkvwb, q_bias, v_bias, qbuf, kbuf, vtbuf, nullptr);
  attn_kernel<<<dim3(294), 256, 0, stream>>>(
      qbuf, kbuf, vtbuf, bias1T, bias2, aout);
  gemm_kernel<1><<<dim3(CDIM / 128, MPAD / 128), 256, 0, stream>>>(
      aout, projwb, proj_b, nullptr, nullptr, nullptr, nullptr, (float*)d_out);
}